// Round 3
// baseline (119.179 us; speedup 1.0000x reference)
//
#include <hip/hip_runtime.h>

// src:  [B=8, C=128, 128, 128] fp32   grid: [B=8, 128, 128, 2] fp32  -> out same shape as src
//
// Structure (this round): 256 persistent blocks (1 per CU) x 1024 threads.
// Each block owns 4 consecutive (b,c) planes (all in the same batch b, since
// 4 | 128). 128 KB dynamic LDS = 2 x 64 KB plane buffers, double-buffered:
// prefetch plane ch+1 via global_load_lds while sampling plane ch.
// Coordinates (idx, wx, wy) for this thread's 16 positions are computed ONCE
// into 48 VGPRs and reused across all 4 planes (they share the batch grid).
//
// HBM: src 64 MB read once (coalesced 16B/lane), out 64 MB written once
// (float4), grid ~1 MB compulsory (re-reads L2-hot). Floor ~21 us @ 6.3 TB/s.

constexpr int PLANE        = 128 * 128;       // floats per plane
constexpr int PLANE_BYTES  = PLANE * 4;       // 64 KiB
constexpr int TPB          = 1024;
constexpr int PPB          = 4;               // planes per block

typedef const __attribute__((address_space(1))) char gchar_t;
typedef __attribute__((address_space(3))) char lchar_t;

__device__ __forceinline__ void coord(float gx, float gy,
                                      int& idx, float& wx, float& wy) {
    // align_corners unnorm: (g+1)*0.5*127 == g*63.5 + 63.5 (single fma, <=1 ulp
    // from reference order; bilinear continuity bounds output diff ~1e-5).
    const float x = fmaf(gx, 63.5f, 63.5f);   // in [0,127]
    const float y = fmaf(gy, 63.5f, 63.5f);
    // floor clamp to <=126 is exactly equivalent to reference OOB masking at
    // the 127 edge; no lower clamp needed (g >= -1 -> x >= 0). Corners are
    // then always idx+{0,1,128,129} -> ds_read2_b32 pairs.
    const float xf = fminf(floorf(x), 126.0f);
    const float yf = fminf(floorf(y), 126.0f);
    wx = x - xf;
    wy = y - yf;
    idx = (int)fmaf(yf, 128.0f, xf);          // exact in fp32 (< 2^24)
}

__device__ __forceinline__ float lerp2(const float* __restrict__ buf,
                                       int idx, float wx, float wy) {
    const float v00 = buf[idx];
    const float v01 = buf[idx + 1];
    const float v10 = buf[idx + 128];
    const float v11 = buf[idx + 129];
    const float v0 = fmaf(wx, v01 - v00, v00);
    const float v1 = fmaf(wx, v11 - v10, v10);
    return fmaf(wy, v1 - v0, v0);
}

__global__ __launch_bounds__(TPB, 4)
void FunctionAffineGridBilinearSample_54039278519070_kernel(
        const float* __restrict__ src,
        const float* __restrict__ grid,
        float* __restrict__ out)
{
    extern __shared__ float lds[];            // 2 * PLANE floats (128 KiB)
    const int tid  = threadIdx.x;
    const int pid0 = blockIdx.x * PPB;        // first plane of this block
    const int b    = pid0 >> 7;               // all 4 planes share batch b

    // ---- issue stage of plane 0 into buf0 (64 KB, 16 B/lane, 4 instrs)
    {
        const char* gs = (const char*)(src + (size_t)pid0 * PLANE);
        char* lb = (char*)lds;
        #pragma unroll
        for (int it = 0; it < 4; ++it) {
            const int off = (it * TPB + tid) * 16;
            __builtin_amdgcn_global_load_lds(
                (gchar_t*)(gs + off), (lchar_t*)(lb + off), 16, 0, 0);
        }
    }

    // ---- coords for this thread's 16 positions, reused by all 4 planes.
    // Overlaps the in-flight staging loads. All indices compile-time (full
    // unroll) so the arrays live in registers, not scratch.
    const float* g2 = grid + ((size_t)b << 15);   // batch grid, [16384][2]
    int   idx[16];
    float wx[16], wy[16];
    #pragma unroll
    for (int i4 = 0; i4 < 4; ++i4) {
        const int p0 = (i4 * TPB + tid) * 4;      // 4 consecutive positions
        const float4 a = *(const float4*)(g2 + 2 * p0);
        const float4 c = *(const float4*)(g2 + 2 * p0 + 4);
        coord(a.x, a.y, idx[i4*4+0], wx[i4*4+0], wy[i4*4+0]);
        coord(a.z, a.w, idx[i4*4+1], wx[i4*4+1], wy[i4*4+1]);
        coord(c.x, c.y, idx[i4*4+2], wx[i4*4+2], wy[i4*4+2]);
        coord(c.z, c.w, idx[i4*4+3], wx[i4*4+3], wy[i4*4+3]);
    }
    __syncthreads();   // compiler drains vmcnt(0) before s_barrier: buf0 ready

    #pragma unroll
    for (int ch = 0; ch < PPB; ++ch) {
        // prefetch next plane into the other buffer (disjoint from the one
        // being read; previous barrier guarantees no straggler still reads it)
        if (ch < PPB - 1) {
            const char* gs = (const char*)(src + (size_t)(pid0 + ch + 1) * PLANE);
            char* lb = (char*)lds + ((ch + 1) & 1) * PLANE_BYTES;
            #pragma unroll
            for (int it = 0; it < 4; ++it) {
                const int off = (it * TPB + tid) * 16;
                __builtin_amdgcn_global_load_lds(
                    (gchar_t*)(gs + off), (lchar_t*)(lb + off), 16, 0, 0);
            }
        }

        const float* buf  = lds + (ch & 1) * PLANE;
        float*       gout = out + (size_t)(pid0 + ch) * PLANE;
        #pragma unroll
        for (int i4 = 0; i4 < 4; ++i4) {
            const int p0 = (i4 * TPB + tid) * 4;
            float4 r;
            r.x = lerp2(buf, idx[i4*4+0], wx[i4*4+0], wy[i4*4+0]);
            r.y = lerp2(buf, idx[i4*4+1], wx[i4*4+1], wy[i4*4+1]);
            r.z = lerp2(buf, idx[i4*4+2], wx[i4*4+2], wy[i4*4+2]);
            r.w = lerp2(buf, idx[i4*4+3], wx[i4*4+3], wy[i4*4+3]);
            *(float4*)(gout + p0) = r;            // coalesced 16 B/lane
        }
        __syncthreads();   // drains this iter's prefetch; protects buffer swap
    }
}

extern "C" void kernel_launch(void* const* d_in, const int* in_sizes, int n_in,
                              void* d_out, int out_size, void* d_ws, size_t ws_size,
                              hipStream_t stream) {
    const float* src  = (const float*)d_in[0];   // 8*128*128*128 fp32
    const float* grid = (const float*)d_in[1];   // 8*128*128*2 fp32
    float* out = (float*)d_out;

    // opt in to >64 KB dynamic LDS (gfx950 allows up to 160 KB/workgroup).
    // Host-side attribute set, not a stream op: graph-capture safe, idempotent.
    hipFuncSetAttribute(
        (const void*)FunctionAffineGridBilinearSample_54039278519070_kernel,
        hipFuncAttributeMaxDynamicSharedMemorySize, 2 * PLANE_BYTES);

    // 1024 planes / 4 per block = 256 blocks = 1 per CU, single round, no tail
    FunctionAffineGridBilinearSample_54039278519070_kernel
        <<<256, TPB, 2 * PLANE_BYTES, stream>>>(src, grid, out);
}